// Round 1
// baseline (558.803 us; speedup 1.0000x reference)
//
#include <hip/hip_runtime.h>
#include <stdint.h>

#define M_DIM 8192
#define N_DIM 4096
#define K_DIM 4096

typedef __attribute__((ext_vector_type(4)))  float  floatx4;
typedef __attribute__((ext_vector_type(16))) float  floatx16;
typedef __attribute__((ext_vector_type(4)))  unsigned int uintx4;
typedef __attribute__((ext_vector_type(2)))  unsigned int uintx2;
typedef __attribute__((ext_vector_type(8)))  _Float16 halfx8;

// ---------------------------------------------------------------------------
// Merged conversion kernel: A (fp32->f16) and W (fp32 * group-scale -> f16).
// Plain CACHED loads/stores (NT hints removed — they defeated L2 line merge on
// the half-line interleave and ran ~1.3 TB/s). Pattern is now perfectly
// coalesced: lane i loads float4 at base+i (1 KiB contiguous per wave instr),
// stores 8 B of f16. Outputs stay cached: a16+w16 = 100 MB fits L3 and is
// exactly what gemm_f16 reads next.
// ---------------------------------------------------------------------------

#define A_F4 (M_DIM * K_DIM / 4)   // 8388608 float4 chunks of A
#define W_F4 (N_DIM * K_DIM / 4)   // 4194304 float4 chunks of W
#define CVT_BLOCKS 2048            // 2048*256 = 524288 threads; 24 iters each

__global__ __launch_bounds__(256) void cvt_all(const float* __restrict__ a_in,
                                               const float* __restrict__ w_in,
                                               const float* __restrict__ scales,
                                               _Float16* __restrict__ a16,
                                               _Float16* __restrict__ w16) {
    const floatx4* a4 = (const floatx4*)a_in;
    const floatx4* w4 = (const floatx4*)w_in;
    uintx2* a2 = (uintx2*)a16;
    uintx2* w2 = (uintx2*)w16;
    const int stride = CVT_BLOCKS * 256;
#pragma unroll 4
    for (int f = blockIdx.x * 256 + threadIdx.x; f < A_F4 + W_F4; f += stride) {
        if (f < A_F4) {
            floatx4 x = a4[f];
            union { _Float16 h[4]; uintx2 u; } p;
            p.h[0] = (_Float16)x[0]; p.h[1] = (_Float16)x[1];
            p.h[2] = (_Float16)x[2]; p.h[3] = (_Float16)x[3];
            a2[f] = p.u;
        } else {
            const int g = f - A_F4;
            const int o = g >> 10;            // K_DIM/4 = 1024 float4 per row
            const int k = (g & 1023) * 4;     // element offset in row
            const float s = scales[(k >> 7) * N_DIM + o];
            floatx4 x = w4[g];
            union { _Float16 h[4]; uintx2 u; } p;
            p.h[0] = (_Float16)(x[0] * s); p.h[1] = (_Float16)(x[1] * s);
            p.h[2] = (_Float16)(x[2] * s); p.h[3] = (_Float16)(x[3] * s);
            w2[g] = p.u;
        }
    }
}

// ---------------------------------------------------------------------------
// f16 GEMM: 128x128 tile, BK=64 (half the barrier drains of BK=32),
// 32x32x16 MFMA (half the MFMA instructions, higher ceiling).
// 256 threads = 4 waves; wave covers 64x64 via 2x2 frags of 32x32.
// LDS rows are 64 halves (128 B); XOR swizzle slot^=(row&7) spreads banks.
// C[m,n] = sum_k A[m,k]*B[n,k] + bias[n]
// (UNCHANGED this round — isolating the cvt delta.)
// ---------------------------------------------------------------------------

__device__ __forceinline__ void gld_lds16(const _Float16* g, _Float16* l) {
    __builtin_amdgcn_global_load_lds(
        (const __attribute__((address_space(1))) void*)g,
        (__attribute__((address_space(3))) void*)l,
        16, 0, 0);
}

__global__ __launch_bounds__(256) void gemm_f16(const _Float16* __restrict__ A,
                                                const _Float16* __restrict__ B,
                                                const float* __restrict__ bias,
                                                float* __restrict__ C) {
    __shared__ _Float16 sA[128 * 64];   // 16 KiB each; LDS slot s of row r
    __shared__ _Float16 sB[128 * 64];   // holds global k-chunk s ^ (r&7)

    const int tid   = threadIdx.x;
    const int wave  = tid >> 6;
    const int lane  = tid & 63;
    const int l32   = lane & 31;
    const int khalf = lane >> 5;        // which 8-wide half of the 16-wide k-step

    const int m0 = blockIdx.y * 128;
    const int n0 = blockIdx.x * 128;
    const int wm = (wave >> 1) * 64;
    const int wn = (wave & 1) * 64;

    // Staging: issue q (0..3) covers chunk c = q*256 + tid.
    // row = c>>3 = q*32 + (tid>>3); LDS slot = tid&7; global chunk = slot ^ (row&7).
    // row&7 == (tid>>3)&7 for every q (q*32 ≡ 0 mod 8) -> one offset for all q.
    const int rbase = tid >> 3;                               // 0..31
    const int g8    = ((tid & 7) ^ ((tid >> 3) & 7)) * 8;     // global k-offset (halves)
    const size_t offG = (size_t)rbase * K_DIM + g8;

    const _Float16* Ab = A + (size_t)m0 * K_DIM;
    const _Float16* Bb = B + (size_t)n0 * K_DIM;

    // Wave-uniform LDS bases (HW adds lane*16 bytes): chunk (q*256 + wave*64)
    _Float16* ldsA[4];
    _Float16* ldsB[4];
#pragma unroll
    for (int q = 0; q < 4; ++q) {
        ldsA[q] = &sA[(q * 256 + wave * 64) * 8];
        ldsB[q] = &sB[(q * 256 + wave * 64) * 8];
    }

    floatx16 acc[2][2] = {};

    for (int k0 = 0; k0 < K_DIM; k0 += 64) {
#pragma unroll
        for (int q = 0; q < 4; ++q) {
            const size_t go = offG + (size_t)q * 32 * K_DIM + k0;
            gld_lds16(Ab + go, ldsA[q]);
            gld_lds16(Bb + go, ldsB[q]);
        }
        __syncthreads();

#pragma unroll
        for (int t = 0; t < 4; ++t) {            // 4 k-steps of 16
            const int slot = ((t * 2 + khalf) ^ (lane & 7)) * 8;
            halfx8 a_frag[2], b_frag[2];
#pragma unroll
            for (int i = 0; i < 2; ++i)
                a_frag[i] = *(const halfx8*)&sA[(wm + i * 32 + l32) * 64 + slot];
#pragma unroll
            for (int j = 0; j < 2; ++j)
                b_frag[j] = *(const halfx8*)&sB[(wn + j * 32 + l32) * 64 + slot];
#pragma unroll
            for (int i = 0; i < 2; ++i)
#pragma unroll
                for (int j = 0; j < 2; ++j)
                    acc[i][j] = __builtin_amdgcn_mfma_f32_32x32x16_f16(
                        a_frag[i], b_frag[j], acc[i][j], 0, 0, 0);
        }
        __syncthreads();
    }

    // Epilogue: 32x32 C/D layout col = lane&31, row = (r&3) + 8*(r>>2) + 4*(lane>>5)
#pragma unroll
    for (int i = 0; i < 2; ++i) {
#pragma unroll
        for (int j = 0; j < 2; ++j) {
            const int n = n0 + wn + j * 32 + l32;
            const float bv = bias[n];
#pragma unroll
            for (int r = 0; r < 16; ++r) {
                const int m = m0 + wm + i * 32 + (r & 3) + 8 * (r >> 2) + 4 * khalf;
                C[(size_t)m * N_DIM + n] = acc[i][j][r] + bv;
            }
        }
    }
}

// ---------------------------------------------------------------------------
// Exact fp32 fallback (only if workspace is too small) — slow but correct.
// ---------------------------------------------------------------------------

__global__ __launch_bounds__(256) void fallback_gemm(const float* __restrict__ A,
                                                     const float* __restrict__ W,
                                                     const float* __restrict__ S,
                                                     const float* __restrict__ bias,
                                                     float* __restrict__ C) {
    const long idx = (long)blockIdx.x * 256 + threadIdx.x;
    const int m = (int)(idx >> 12);
    const int n = (int)(idx & 4095);
    const float* a = A + (size_t)m * K_DIM;
    const float* w = W + (size_t)n * K_DIM;
    float acc = 0.f;
    for (int g = 0; g < 32; ++g) {
        const float s = S[g * N_DIM + n];
        float part = 0.f;
        const int kb = g * 128;
#pragma unroll 4
        for (int k = kb; k < kb + 128; ++k) part += a[k] * w[k];
        acc += part * s;
    }
    C[idx] = acc + bias[n];
}

// ---------------------------------------------------------------------------

extern "C" void kernel_launch(void* const* d_in, const int* in_sizes, int n_in,
                              void* d_out, int out_size, void* d_ws, size_t ws_size,
                              hipStream_t stream) {
    const float* input   = (const float*)d_in[0];
    const float* qweight = (const float*)d_in[1];
    const float* scales  = (const float*)d_in[2];
    const float* bias    = (const float*)d_in[3];
    float* out = (float*)d_out;

    const size_t a_bytes = (size_t)M_DIM * K_DIM * sizeof(_Float16); // 64 MiB
    const size_t w_bytes = (size_t)N_DIM * K_DIM * sizeof(_Float16); // 32 MiB

    if (ws_size >= a_bytes + w_bytes) {
        _Float16* a16 = (_Float16*)d_ws;
        _Float16* w16 = (_Float16*)((char*)d_ws + a_bytes);

        cvt_all<<<CVT_BLOCKS, 256, 0, stream>>>(input, qweight, scales, a16, w16);

        dim3 grid(N_DIM / 128, M_DIM / 128);   // (32, 64)
        gemm_f16<<<grid, 256, 0, stream>>>(a16, w16, bias, out);
    } else {
        fallback_gemm<<<((size_t)M_DIM * N_DIM) / 256, 256, 0, stream>>>(
            input, qweight, scales, bias, out);
    }
}

// Round 2
// 487.303 us; speedup vs baseline: 1.1467x; 1.1467x over previous
//
#include <hip/hip_runtime.h>
#include <stdint.h>

#define M_DIM 8192
#define N_DIM 4096
#define K_DIM 4096
#define NKT   (K_DIM / 64)

typedef __attribute__((ext_vector_type(4)))  float  floatx4;
typedef __attribute__((ext_vector_type(4)))  unsigned int uintx4;
typedef __attribute__((ext_vector_type(2)))  unsigned int uintx2;
typedef __attribute__((ext_vector_type(8)))  _Float16 halfx8;

// ---------------------------------------------------------------------------
// Conversion kernel (UNCHANGED this round): A fp32->f16, W fp32*scale->f16.
// Coalesced float4 loads, 8B f16 stores, grid-stride.
// ---------------------------------------------------------------------------

#define A_F4 (M_DIM * K_DIM / 4)
#define W_F4 (N_DIM * K_DIM / 4)
#define CVT_BLOCKS 2048

__global__ __launch_bounds__(256) void cvt_all(const float* __restrict__ a_in,
                                               const float* __restrict__ w_in,
                                               const float* __restrict__ scales,
                                               _Float16* __restrict__ a16,
                                               _Float16* __restrict__ w16) {
    const floatx4* a4 = (const floatx4*)a_in;
    const floatx4* w4 = (const floatx4*)w_in;
    uintx2* a2 = (uintx2*)a16;
    uintx2* w2 = (uintx2*)w16;
    const int stride = CVT_BLOCKS * 256;
#pragma unroll 4
    for (int f = blockIdx.x * 256 + threadIdx.x; f < A_F4 + W_F4; f += stride) {
        if (f < A_F4) {
            floatx4 x = a4[f];
            union { _Float16 h[4]; uintx2 u; } p;
            p.h[0] = (_Float16)x[0]; p.h[1] = (_Float16)x[1];
            p.h[2] = (_Float16)x[2]; p.h[3] = (_Float16)x[3];
            a2[f] = p.u;
        } else {
            const int g = f - A_F4;
            const int o = g >> 10;
            const int k = (g & 1023) * 4;
            const float s = scales[(k >> 7) * N_DIM + o];
            floatx4 x = w4[g];
            union { _Float16 h[4]; uintx2 u; } p;
            p.h[0] = (_Float16)(x[0] * s); p.h[1] = (_Float16)(x[1] * s);
            p.h[2] = (_Float16)(x[2] * s); p.h[3] = (_Float16)(x[3] * s);
            w2[g] = p.u;
        }
    }
}

// ---------------------------------------------------------------------------
// 256x256 8-phase GEMM, BK=64, 512 threads (8 waves as 2x4), 16x16x32 f16 MFMA.
// Counted vmcnt pipeline: prefetch kt+1's half-tiles {A0,B0,B1,A1} one per
// phase while computing kt's quadrants {A0B0, A0B1, A1B1, A1B0}.
// Per-wave vmcnt(4) + raw s_barrier vouches half-tile landings; queue never
// drains below 2 half-tiles in the main loop.
// Frag->row interleave: wave (wr,wc) m-frag i -> rows (i&3)*32+wr*16+(i>>2)*128
// so every wave needs both A halves and both B halves (makes the counted
// waits uniform across waves).
// LDS: [2][256][64] halves per matrix = 64 KiB each, 128 KiB total (dynamic).
// Swizzle: row r, k-chunk c (8 halves) stored at slot c^(r&7); staged via
// pre-swizzled global source + linear gld_lds dest (both-sides rule).
// ---------------------------------------------------------------------------

__device__ __forceinline__ void gld_lds16(const _Float16* g, _Float16* l) {
    __builtin_amdgcn_global_load_lds(
        (const __attribute__((address_space(1))) void*)g,
        (__attribute__((address_space(3))) void*)l, 16, 0, 0);
}

#define WAITV(n) asm volatile("s_waitcnt vmcnt(" #n ")" ::: "memory")
#define BAR()    asm volatile("s_barrier" ::: "memory")

__device__ __forceinline__ void issue_half(const _Float16* gbase, _Float16* sbase,
                                           int b, int h, int kcol, int wid) {
#pragma unroll
    for (int q2 = 0; q2 < 2; ++q2) {
        const int q = 2 * h + q2;
        gld_lds16(gbase + (size_t)q * 64 * K_DIM + kcol,
                  sbase + b * 16384 + q * 4096 + wid * 512);
    }
}

__device__ __forceinline__ void load_a(halfx8 af[4][2], const _Float16* sA, int b,
                                       int ih, int wr, int l15, int sl0, int sl1) {
#pragma unroll
    for (int il = 0; il < 4; ++il) {
        const int ro = b * 16384 + (ih * 128 + il * 32 + wr * 16 + l15) * 64;
        af[il][0] = *(const halfx8*)&sA[ro + sl0];
        af[il][1] = *(const halfx8*)&sA[ro + sl1];
    }
}

__device__ __forceinline__ void load_b(halfx8 bf[2][2], const _Float16* sB, int b,
                                       int jh, int wc, int l15, int sl0, int sl1) {
#pragma unroll
    for (int jl = 0; jl < 2; ++jl) {
        const int ro = b * 16384 + (jh * 128 + jl * 64 + wc * 16 + l15) * 64;
        bf[jl][0] = *(const halfx8*)&sB[ro + sl0];
        bf[jl][1] = *(const halfx8*)&sB[ro + sl1];
    }
}

__device__ __forceinline__ void mfma_q(floatx4 acc[8][4], int ih, int jh,
                                       const halfx8 af[4][2], const halfx8 bf[2][2]) {
    __builtin_amdgcn_s_setprio(1);
#pragma unroll
    for (int il = 0; il < 4; ++il)
#pragma unroll
    for (int jl = 0; jl < 2; ++jl)
#pragma unroll
    for (int ks = 0; ks < 2; ++ks)
        acc[ih * 4 + il][jh * 2 + jl] = __builtin_amdgcn_mfma_f32_16x16x32_f16(
            af[il][ks], bf[jl][ks], acc[ih * 4 + il][jh * 2 + jl], 0, 0, 0);
    __builtin_amdgcn_s_setprio(0);
}

__global__ __launch_bounds__(512, 2) void gemm_f16(const _Float16* __restrict__ A,
                                                   const _Float16* __restrict__ B,
                                                   const float* __restrict__ bias,
                                                   float* __restrict__ C) {
    extern __shared__ _Float16 lds[];
    _Float16* sA = lds;                 // [2][256][64]
    _Float16* sB = lds + 2 * 256 * 64;  // [2][256][64]

    const int tid  = threadIdx.x;
    const int wid  = tid >> 6;
    const int lane = tid & 63;
    const int wr   = wid >> 2;          // 0..1
    const int wc   = wid & 3;           // 0..3
    const int l15  = lane & 15;
    const int lk   = lane >> 4;         // 0..3

    const int m0 = blockIdx.y * 256;
    const int n0 = blockIdx.x * 256;

    // Staging: issue q covers rows q*64 + (tid>>3); slot tid&7 holds global
    // chunk (tid&7)^(row&7).  (q*64 ≡ 0 mod 8 -> offset constant across q.)
    const int rowt = tid >> 3;
    const int g8   = ((tid & 7) ^ ((tid >> 3) & 7)) * 8;
    const _Float16* Abase = A + (size_t)(m0 + rowt) * K_DIM + g8;
    const _Float16* Bbase = B + (size_t)(n0 + rowt) * K_DIM + g8;

    // Fragment read: chunk c = ks*4 + lk of row r lives at slot c^(r&7);
    // r&7 == lane&7 for all frag rows (bases are multiples of 16).
    const int sl0 = ((lk) ^ (lane & 7)) * 8;
    const int sl1 = sl0 ^ 32;

    floatx4 acc[8][4] = {};
    halfx8 af[4][2], bf0[2][2], bf1[2][2];

    // Prologue: stage kt=0 into buf 0 in wait-order A0, B0, B1, A1 (8 loads/wave).
    issue_half(Abase, sA, 0, 0, 0, wid);
    issue_half(Bbase, sB, 0, 0, 0, wid);
    issue_half(Bbase, sB, 0, 1, 0, wid);
    issue_half(Abase, sA, 0, 1, 0, wid);

    for (int kt = 0; kt < NKT - 1; ++kt) {
        const int b  = kt & 1;
        const int nb = b ^ 1;
        const int kn = (kt + 1) * 64;
        // P1: quadrant A0xB0; needs A0,B0(kt) -> oldest 4 ops of 8 in flight.
        WAITV(4); BAR();
        issue_half(Abase, sA, nb, 0, kn, wid);       // A0(kt+1)
        load_a(af, sA, b, 0, wr, l15, sl0, sl1);
        load_b(bf0, sB, b, 0, wc, l15, sl0, sl1);
        mfma_q(acc, 0, 0, af, bf0);
        // P2: A0xB1; needs B1(kt) -> vmcnt(4) leaves {A1(kt), A0(kt+1)}.
        WAITV(4); BAR();
        issue_half(Bbase, sB, nb, 0, kn, wid);       // B0(kt+1)
        load_b(bf1, sB, b, 1, wc, l15, sl0, sl1);
        mfma_q(acc, 0, 1, af, bf1);
        // P3: A1xB1; needs A1(kt) -> vmcnt(4) leaves {A0(kt+1), B0(kt+1)}.
        WAITV(4); BAR();
        issue_half(Bbase, sB, nb, 1, kn, wid);       // B1(kt+1)
        load_a(af, sA, b, 1, wr, l15, sl0, sl1);
        mfma_q(acc, 1, 1, af, bf1);
        // P4: A1xB0; all in registers -> no wait, no barrier.
        issue_half(Abase, sA, nb, 1, kn, wid);       // A1(kt+1)
        mfma_q(acc, 1, 0, af, bf0);
    }

    // Last K-tile: nothing left to issue; tighten the counts (4/2/0).
    {
        const int b = (NKT - 1) & 1;
        WAITV(4); BAR();
        load_a(af, sA, b, 0, wr, l15, sl0, sl1);
        load_b(bf0, sB, b, 0, wc, l15, sl0, sl1);
        mfma_q(acc, 0, 0, af, bf0);
        WAITV(2); BAR();
        load_b(bf1, sB, b, 1, wc, l15, sl0, sl1);
        mfma_q(acc, 0, 1, af, bf1);
        WAITV(0); BAR();
        load_a(af, sA, b, 1, wr, l15, sl0, sl1);
        mfma_q(acc, 1, 1, af, bf1);
        mfma_q(acc, 1, 0, af, bf0);
    }

    // Epilogue: 16x16 C/D layout col = lane&15, row = (lane>>4)*4 + reg.
#pragma unroll
    for (int ih = 0; ih < 2; ++ih)
#pragma unroll
    for (int il = 0; il < 4; ++il)
#pragma unroll
    for (int jh = 0; jh < 2; ++jh)
#pragma unroll
    for (int jl = 0; jl < 2; ++jl) {
        const int n = n0 + jh * 128 + jl * 64 + wc * 16 + l15;
        const float bv = bias[n];
        const int mb = m0 + ih * 128 + il * 32 + wr * 16 + lk * 4;
        const floatx4 v = acc[ih * 4 + il][jh * 2 + jl];
#pragma unroll
        for (int r = 0; r < 4; ++r)
            C[(size_t)(mb + r) * N_DIM + n] = v[r] + bv;
    }
}

// ---------------------------------------------------------------------------
// Exact fp32 fallback (only if workspace is too small) — slow but correct.
// ---------------------------------------------------------------------------

__global__ __launch_bounds__(256) void fallback_gemm(const float* __restrict__ A,
                                                     const float* __restrict__ W,
                                                     const float* __restrict__ S,
                                                     const float* __restrict__ bias,
                                                     float* __restrict__ C) {
    const long idx = (long)blockIdx.x * 256 + threadIdx.x;
    const int m = (int)(idx >> 12);
    const int n = (int)(idx & 4095);
    const float* a = A + (size_t)m * K_DIM;
    const float* w = W + (size_t)n * K_DIM;
    float acc = 0.f;
    for (int g = 0; g < 32; ++g) {
        const float s = S[g * N_DIM + n];
        float part = 0.f;
        const int kb = g * 128;
#pragma unroll 4
        for (int k = kb; k < kb + 128; ++k) part += a[k] * w[k];
        acc += part * s;
    }
    C[idx] = acc + bias[n];
}

// ---------------------------------------------------------------------------

extern "C" void kernel_launch(void* const* d_in, const int* in_sizes, int n_in,
                              void* d_out, int out_size, void* d_ws, size_t ws_size,
                              hipStream_t stream) {
    const float* input   = (const float*)d_in[0];
    const float* qweight = (const float*)d_in[1];
    const float* scales  = (const float*)d_in[2];
    const float* bias    = (const float*)d_in[3];
    float* out = (float*)d_out;

    const size_t a_bytes = (size_t)M_DIM * K_DIM * sizeof(_Float16); // 64 MiB
    const size_t w_bytes = (size_t)N_DIM * K_DIM * sizeof(_Float16); // 32 MiB

    if (ws_size >= a_bytes + w_bytes) {
        _Float16* a16 = (_Float16*)d_ws;
        _Float16* w16 = (_Float16*)((char*)d_ws + a_bytes);

        cvt_all<<<CVT_BLOCKS, 256, 0, stream>>>(input, qweight, scales, a16, w16);

        // 128 KiB dynamic LDS: raise the per-kernel cap (no-op if already allowed).
        static bool attr_done = false;
        if (!attr_done) {
            (void)hipFuncSetAttribute((const void*)gemm_f16,
                                      hipFuncAttributeMaxDynamicSharedMemorySize,
                                      131072);
            attr_done = true;
        }
        dim3 grid(N_DIM / 256, M_DIM / 256);   // (16, 32)
        gemm_f16<<<grid, 512, 131072, stream>>>(a16, w16, bias, out);
    } else {
        fallback_gemm<<<((size_t)M_DIM * N_DIM) / 256, 256, 0, stream>>>(
            input, qweight, scales, bias, out);
    }
}